// Round 15
// baseline (422.186 us; speedup 1.0000x reference)
//
#include <hip/hip_runtime.h>
#include <math.h>

#define S_LEN 512
#define D_DIM 256
#define SLICE (S_LEN * D_DIM)   // 131072

typedef _Float16 half8  __attribute__((ext_vector_type(8)));
typedef _Float16 half4v __attribute__((ext_vector_type(4)));
typedef float   floatx4 __attribute__((ext_vector_type(4)));

// ---------------------------------------------------------------------------
// WlhT[d][e] = fp16(Wl[e][d] + (e==d))     (raw + raw@Wl == raw@(I+Wl))
// ---------------------------------------------------------------------------
__global__ __launch_bounds__(256) void prep_wl(const float* __restrict__ Wl,
                                               _Float16* __restrict__ WlhT)
{
    const int d = blockIdx.x, e = threadIdx.x;
    float v = Wl[e * D_DIM + d] + (e == d ? 1.0f : 0.0f);
    WlhT[d * D_DIM + e] = (_Float16)v;
}

// ---------------------------------------------------------------------------
// fp32 -> fp16 copies of k and q (post-linres)
// ---------------------------------------------------------------------------
__global__ __launch_bounds__(256) void cvt_fp16(const float* __restrict__ kf,
                                                const float* __restrict__ qf,
                                                _Float16* __restrict__ kh,
                                                _Float16* __restrict__ qh)
{
    const int i = (blockIdx.x * 256 + threadIdx.x) * 4;
    float4 a = *(const float4*)(kf + i);
    float4 b = *(const float4*)(qf + i);
    half4v ah = { (_Float16)a.x, (_Float16)a.y, (_Float16)a.z, (_Float16)a.w };
    half4v bh = { (_Float16)b.x, (_Float16)b.y, (_Float16)b.z, (_Float16)b.w };
    *(half4v*)(kh + i) = ah;
    *(half4v*)(qh + i) = bh;
}

// ---------------------------------------------------------------------------
// y = x + x@W + b  for [512,256]@[256,256]; 4 rows per block (fp32, small).
// ---------------------------------------------------------------------------
__global__ __launch_bounds__(256) void linres3(
    const float* __restrict__ xk, const float* __restrict__ Wk,
    const float* __restrict__ bk, float* __restrict__ yk,
    const float* __restrict__ xq, const float* __restrict__ Wq,
    const float* __restrict__ bq, float* __restrict__ yq,
    const float* __restrict__ xv, const float* __restrict__ Wv,
    const float* __restrict__ bv, float* __restrict__ yv)
{
    __shared__ float xs[4][D_DIM];
    const int r0 = blockIdx.x * 4;
    const int sel = blockIdx.y;
    const float* x = sel == 0 ? xk : (sel == 1 ? xq : xv);
    const float* W = sel == 0 ? Wk : (sel == 1 ? Wq : Wv);
    const float* b = sel == 0 ? bk : (sel == 1 ? bq : bv);
    float*       y = sel == 0 ? yk : (sel == 1 ? yq : yv);

    const int tid = threadIdx.x;
    #pragma unroll
    for (int t = 0; t < 4; ++t) xs[t][tid] = x[(r0 + t) * D_DIM + tid];
    __syncthreads();
    const float bv_ = b[tid];
    float acc[4];
    #pragma unroll
    for (int i = 0; i < 4; ++i) acc[i] = xs[i][tid] + bv_;
    #pragma unroll 4
    for (int e = 0; e < D_DIM; ++e) {
        const float w = W[e * D_DIM + tid];
        #pragma unroll
        for (int i = 0; i < 4; ++i) acc[i] += xs[i][e] * w;
    }
    #pragma unroll
    for (int i = 0; i < 4; ++i) y[(r0 + i) * D_DIM + tid] = acc[i];
}

// ---------------------------------------------------------------------------
// Final linear with partial-sum fusion: x = sum_c po[c]; out = x + x@W + b
// ---------------------------------------------------------------------------
__global__ __launch_bounds__(256) void linres_sum(
    const float* __restrict__ po, const float* __restrict__ W,
    const float* __restrict__ b, float* __restrict__ y)
{
    __shared__ float xs[4][D_DIM];
    const int tid = threadIdx.x;
    const int r0  = blockIdx.x * 4;
    #pragma unroll
    for (int t = 0; t < 4; ++t) {
        float s = 0.f;
        #pragma unroll
        for (int c = 0; c < 16; ++c)
            s += po[(size_t)c * SLICE + (r0 + t) * D_DIM + tid];
        xs[t][tid] = s;
    }
    __syncthreads();
    const float bv_ = b[tid];
    float acc[4];
    #pragma unroll
    for (int i = 0; i < 4; ++i) acc[i] = xs[i][tid] + bv_;
    #pragma unroll 4
    for (int e = 0; e < D_DIM; ++e) {
        const float w = W[e * D_DIM + tid];
        #pragma unroll
        for (int i = 0; i < 4; ++i) acc[i] += xs[i][e] * w;
    }
    #pragma unroll
    for (int i = 0; i < 4; ++i) y[(r0 + i) * D_DIM + tid] = acc[i];
}

// ---------------------------------------------------------------------------
// Stage 64x256 fp16 q tile into fragment-major LDS (R3/R7/R11-proven):
// fb = mt*8+kk; slot = quad*16+l16; addr16 = fb*64 + slot. Conflict-free.
// ---------------------------------------------------------------------------
__device__ __forceinline__ void stage_q(const _Float16* __restrict__ qh,
                                        _Float16* __restrict__ Afrag,
                                        int sq0, int tid)
{
    const int i   = tid & 63;   // row within tile
    const int qtr = tid >> 6;   // e-quarter (64 elems)
    const int mt = i >> 4, l16 = i & 15;
    const half8* src = (const half8*)(qh + (size_t)(sq0 + i) * D_DIM + qtr * 64);
    #pragma unroll
    for (int u = 0; u < 8; ++u) {
        const int eb   = qtr * 8 + u;           // e-block (8 halfs) 0..31
        const int kk   = eb >> 2, quad = eb & 3;
        const int addr16 = (mt * 8 + kk) * 64 + quad * 16 + l16;
        *(half8*)(Afrag + addr16 * 8) = src[u];
    }
}

// Same layout for a 32-row tile (mt in {0,1}), 4 half8 per thread (R8-proven).
__device__ __forceinline__ void stage_q32(const _Float16* __restrict__ qh,
                                          _Float16* __restrict__ Afrag,
                                          int sq0, int tid)
{
    const int i   = tid & 31;   // row within tile
    const int oct = tid >> 5;   // e-eighth (32 halfs)
    const int mt = i >> 4, l16 = i & 15;
    const half8* src = (const half8*)(qh + (size_t)(sq0 + i) * D_DIM);
    #pragma unroll
    for (int u = 0; u < 4; ++u) {
        const int eb   = oct * 4 + u;           // e-block (8 halfs) 0..31
        const int kk   = eb >> 2, quad = eb & 3;
        const int addr16 = (mt * 8 + kk) * 64 + quad * 16 + l16;
        *(half8*)(Afrag + addr16 * 8) = src[eb];
    }
}

// ---------------------------------------------------------------------------
// Stats: per-(sk,d) tile-partial (max, sum |L| e^(L-max)) over 64 sq rows.
// Grid (8 sq-tiles, 4 d-quarters, 32 sk-chunks of 16) = 1024 blocks (4/CU —
// R12 showed 2/CU leaves 44% of cycles stalled). Wave strip d16 (nt=1):
// wl[8]=32 VGPR; VGPR <=128 enforced by __launch_bounds__(256,4).
// kk loop FULLY unrolled (partial unroll demotes wl to scratch — R7-R9 bug).
// ---------------------------------------------------------------------------
__global__ __launch_bounds__(256, 4) void stats_mfma(
    const _Float16* __restrict__ qh, const _Float16* __restrict__ kh,
    const _Float16* __restrict__ WlhT, const float* __restrict__ bl,
    float* __restrict__ pm, float* __restrict__ ps)
{
    __shared__ _Float16 Afrag[32 * 64 * 8];   // 32 KB

    const int tid  = threadIdx.x;
    const int lane = tid & 63, wave = tid >> 6;
    const int quad = lane >> 4, l16 = lane & 15;
    const int sqt  = blockIdx.x, sq0 = sqt * 64;
    const int dw   = blockIdx.y * 64 + wave * 16;
    const int sk0  = blockIdx.z * 16;
    const int d    = dw + l16;

    stage_q(qh, Afrag, sq0, tid);

    half8 wl[8];
    #pragma unroll
    for (int kk = 0; kk < 8; ++kk)
        wl[kk] = *(const half8*)(WlhT + (size_t)d * D_DIM + kk * 32 + quad * 8);
    const float bl_r = bl[d];

    __syncthreads();

    #pragma unroll 1
    for (int s = 0; s < 16; ++s) {
        const int sk = sk0 + s;
        floatx4 acc[4];
        #pragma unroll
        for (int mt = 0; mt < 4; ++mt)
            acc[mt] = (floatx4){0.f, 0.f, 0.f, 0.f};

        #pragma unroll
        for (int kk = 0; kk < 8; ++kk) {
            const half8 k8 = *(const half8*)(kh + (size_t)sk * D_DIM + kk * 32 + quad * 8);
            const half8 bf = wl[kk] * k8;
            half8 af[4];
            #pragma unroll
            for (int mt = 0; mt < 4; ++mt)
                af[mt] = *(const half8*)(Afrag + ((mt * 8 + kk) * 64 + lane) * 8);
            #pragma unroll
            for (int mt = 0; mt < 4; ++mt)
                acc[mt] = __builtin_amdgcn_mfma_f32_16x16x32_f16(
                    af[mt], bf, acc[mt], 0, 0, 0);
        }

        float Lv[4][4];
        float tmax = -1e30f;
        #pragma unroll
        for (int mt = 0; mt < 4; ++mt)
            #pragma unroll
            for (int r = 0; r < 4; ++r) {
                const float L = acc[mt][r] + bl_r;
                Lv[mt][r] = L;
                tmax = fmaxf(tmax, L);
            }
        float tsum = 0.f;
        #pragma unroll
        for (int mt = 0; mt < 4; ++mt)
            #pragma unroll
            for (int r = 0; r < 4; ++r)
                tsum += fabsf(Lv[mt][r]) * __expf(Lv[mt][r] - tmax);

        float m = tmax, ss = tsum;
        #pragma unroll
        for (int mask = 16; mask <= 32; mask <<= 1) {
            float m2 = __shfl_xor(m, mask, 64);
            float s2 = __shfl_xor(ss, mask, 64);
            float M  = fmaxf(m, m2);
            ss = ss * __expf(m - M) + s2 * __expf(m2 - M);
            m = M;
        }
        if (quad == 0) {
            pm[((size_t)sqt * S_LEN + sk) * D_DIM + d] = m;
            ps[((size_t)sqt * S_LEN + sk) * D_DIM + d] = ss;
        }
    }
}

// ---------------------------------------------------------------------------
// Merge the 8 sq-tile partials -> mbuf, sbuf  (R3/R7/R11-proven)
// ---------------------------------------------------------------------------
__global__ __launch_bounds__(256) void reduce_ms(
    const float* __restrict__ pm, const float* __restrict__ ps,
    float* __restrict__ mbuf, float* __restrict__ sbuf)
{
    const int idx = blockIdx.x * 256 + threadIdx.x;   // (sk,d), 131072 total
    float m = pm[idx], ss = ps[idx];
    #pragma unroll
    for (int t = 1; t < 8; ++t) {
        const float m2 = pm[t * SLICE + idx];
        const float s2 = ps[t * SLICE + idx];
        const float M  = fmaxf(m, m2);
        ss = ss * __expf(m - M) + s2 * __expf(m2 - M);
        m = M;
    }
    mbuf[idx] = m;
    sbuf[idx] = ss;
}

// ---------------------------------------------------------------------------
// Accum: recompute L, p = L e^(L-m)/(S+1); o += v[sk,d]*p over 32 sk;
// PLAIN stores of the 32x64 fp32 partial tile to po[chunk] (no atomics —
// 8.4M device RMW atomics were R7/R11's ~110 us floor).
// Grid (16 sq-tiles of 32, 4 d-quarters, 16 sk-chunks of 32) = 1024 blocks.
// Wave strip d16 (nt=1). kk loop FULLY unrolled (wl in VGPRs).
// ---------------------------------------------------------------------------
__global__ __launch_bounds__(256, 4) void accum_mfma(
    const _Float16* __restrict__ qh, const _Float16* __restrict__ kh,
    const _Float16* __restrict__ WlhT, const float* __restrict__ bl,
    const float* __restrict__ mbuf, const float* __restrict__ sbuf,
    const float* __restrict__ vbuf, float* __restrict__ po)
{
    __shared__ _Float16 Afrag[16 * 64 * 8];   // 16 KB

    const int tid  = threadIdx.x;
    const int lane = tid & 63, wave = tid >> 6;
    const int quad = lane >> 4, l16 = lane & 15;
    const int sq0  = blockIdx.x * 32;
    const int dw   = blockIdx.y * 64 + wave * 16;
    const int chunk = blockIdx.z;
    const int sk0  = chunk * 32;
    const int d    = dw + l16;

    stage_q32(qh, Afrag, sq0, tid);

    half8 wl[8];
    #pragma unroll
    for (int kk = 0; kk < 8; ++kk)
        wl[kk] = *(const half8*)(WlhT + (size_t)d * D_DIM + kk * 32 + quad * 8);
    const float bl_r = bl[d];

    floatx4 o[2];
    o[0] = (floatx4){0.f, 0.f, 0.f, 0.f};
    o[1] = (floatx4){0.f, 0.f, 0.f, 0.f};

    __syncthreads();

    #pragma unroll 1
    for (int s = 0; s < 32; ++s) {
        const int sk = sk0 + s;
        floatx4 acc[2];
        acc[0] = (floatx4){0.f, 0.f, 0.f, 0.f};
        acc[1] = (floatx4){0.f, 0.f, 0.f, 0.f};

        #pragma unroll
        for (int kk = 0; kk < 8; ++kk) {
            const half8 k8 = *(const half8*)(kh + (size_t)sk * D_DIM + kk * 32 + quad * 8);
            const half8 bf = wl[kk] * k8;
            half8 af0 = *(const half8*)(Afrag + ((0 * 8 + kk) * 64 + lane) * 8);
            half8 af1 = *(const half8*)(Afrag + ((1 * 8 + kk) * 64 + lane) * 8);
            acc[0] = __builtin_amdgcn_mfma_f32_16x16x32_f16(af0, bf, acc[0], 0, 0, 0);
            acc[1] = __builtin_amdgcn_mfma_f32_16x16x32_f16(af1, bf, acc[1], 0, 0, 0);
        }

        const float m_r = mbuf[(size_t)sk * D_DIM + d];
        const float inv = 1.0f / (sbuf[(size_t)sk * D_DIM + d] + 1.0f);
        const float vv  = vbuf[(size_t)sk * D_DIM + d];
        #pragma unroll
        for (int mt = 0; mt < 2; ++mt)
            #pragma unroll
            for (int r = 0; r < 4; ++r) {
                const float L = acc[mt][r] + bl_r;
                const float p = L * __expf(L - m_r) * inv;
                o[mt][r] += vv * p;
            }
    }

    float* dst = po + (size_t)chunk * SLICE;
    #pragma unroll
    for (int mt = 0; mt < 2; ++mt)
        #pragma unroll
        for (int r = 0; r < 4; ++r) {
            const int row = sq0 + mt * 16 + quad * 4 + r;
            dst[(size_t)row * D_DIM + d] = o[mt][r];
        }
}

// ---------------------------------------------------------------------------
extern "C" void kernel_launch(void* const* d_in, const int* in_sizes, int n_in,
                              void* d_out, int out_size, void* d_ws, size_t ws_size,
                              hipStream_t stream)
{
    const float* query = (const float*)d_in[0];
    const float* key   = (const float*)d_in[1];
    const float* value = (const float*)d_in[2];
    const float* Wk  = (const float*)d_in[3];
    const float* bk  = (const float*)d_in[4];
    const float* Wq  = (const float*)d_in[5];
    const float* bq  = (const float*)d_in[6];
    const float* Wva = (const float*)d_in[7];
    const float* bva = (const float*)d_in[8];
    const float* Wl  = (const float*)d_in[9];
    const float* bl  = (const float*)d_in[10];
    const float* Wvo = (const float*)d_in[11];
    const float* bvo = (const float*)d_in[12];

    const int MAT = SLICE;                    // 131072
    float* ws   = (float*)d_ws;
    // R11/R12-proven footprint; po overlays dead pm+ps.
    float* kbuf = ws;
    float* qbuf = ws + MAT;
    float* vbuf = ws + 2 * MAT;
    float* mbuf = ws + 3 * MAT;
    float* sbuf = ws + 4 * MAT;
    _Float16* WlhT = (_Float16*)(ws + 6 * MAT);            // 128 KB
    _Float16* kh   = (_Float16*)(ws + 6 * MAT + 32768);    // 256 KB
    _Float16* qh   = kh + MAT;                             // 256 KB
    float* pm  = ws + 6 * MAT + 32768 + 2 * 65536;         // 4 MB
    float* ps  = pm + 8 * MAT;                             // 4 MB
    float* po  = pm;   // 16*MAT floats (8 MB), pm/ps dead after reduce_ms
    float* out = (float*)d_out;

    prep_wl<<<256, 256, 0, stream>>>(Wl, WlhT);
    linres3<<<dim3(128, 3), 256, 0, stream>>>(key, Wk, bk, kbuf,
                                              query, Wq, bq, qbuf,
                                              value, Wva, bva, vbuf);
    cvt_fp16<<<128, 256, 0, stream>>>(kbuf, qbuf, kh, qh);

    stats_mfma<<<dim3(8, 4, 32), 256, 0, stream>>>(qh, kh, WlhT, bl, pm, ps);
    reduce_ms<<<512, 256, 0, stream>>>(pm, ps, mbuf, sbuf);
    accum_mfma<<<dim3(16, 4, 16), 256, 0, stream>>>(qh, kh, WlhT, bl,
                                                    mbuf, sbuf, vbuf, po);

    linres_sum<<<128, 256, 0, stream>>>(po, Wvo, bvo, out);
}

// Round 16
// 299.323 us; speedup vs baseline: 1.4105x; 1.4105x over previous
//
#include <hip/hip_runtime.h>
#include <math.h>

#define S_LEN 512
#define D_DIM 256
#define SLICE (S_LEN * D_DIM)   // 131072
#define NCH 8                    // accum partial slices (chunks of 64 sk)

typedef _Float16 half8  __attribute__((ext_vector_type(8)));
typedef _Float16 half4v __attribute__((ext_vector_type(4)));
typedef float   floatx4 __attribute__((ext_vector_type(4)));

// ---------------------------------------------------------------------------
// WlhT[d][e] = fp16(Wl[e][d] + (e==d))     (raw + raw@Wl == raw@(I+Wl))
// ---------------------------------------------------------------------------
__global__ __launch_bounds__(256) void prep_wl(const float* __restrict__ Wl,
                                               _Float16* __restrict__ WlhT)
{
    const int d = blockIdx.x, e = threadIdx.x;
    float v = Wl[e * D_DIM + d] + (e == d ? 1.0f : 0.0f);
    WlhT[d * D_DIM + e] = (_Float16)v;
}

// ---------------------------------------------------------------------------
// fp32 -> fp16 copies of k and q (post-linres)
// ---------------------------------------------------------------------------
__global__ __launch_bounds__(256) void cvt_fp16(const float* __restrict__ kf,
                                                const float* __restrict__ qf,
                                                _Float16* __restrict__ kh,
                                                _Float16* __restrict__ qh)
{
    const int i = (blockIdx.x * 256 + threadIdx.x) * 4;
    float4 a = *(const float4*)(kf + i);
    float4 b = *(const float4*)(qf + i);
    half4v ah = { (_Float16)a.x, (_Float16)a.y, (_Float16)a.z, (_Float16)a.w };
    half4v bh = { (_Float16)b.x, (_Float16)b.y, (_Float16)b.z, (_Float16)b.w };
    *(half4v*)(kh + i) = ah;
    *(half4v*)(qh + i) = bh;
}

// ---------------------------------------------------------------------------
// y = x + x@W + b  for [512,256]@[256,256]; 4 rows per block (fp32, small).
// ---------------------------------------------------------------------------
__global__ __launch_bounds__(256) void linres3(
    const float* __restrict__ xk, const float* __restrict__ Wk,
    const float* __restrict__ bk, float* __restrict__ yk,
    const float* __restrict__ xq, const float* __restrict__ Wq,
    const float* __restrict__ bq, float* __restrict__ yq,
    const float* __restrict__ xv, const float* __restrict__ Wv,
    const float* __restrict__ bv, float* __restrict__ yv)
{
    __shared__ float xs[4][D_DIM];
    const int r0 = blockIdx.x * 4;
    const int sel = blockIdx.y;
    const float* x = sel == 0 ? xk : (sel == 1 ? xq : xv);
    const float* W = sel == 0 ? Wk : (sel == 1 ? Wq : Wv);
    const float* b = sel == 0 ? bk : (sel == 1 ? bq : bv);
    float*       y = sel == 0 ? yk : (sel == 1 ? yq : yv);

    const int tid = threadIdx.x;
    #pragma unroll
    for (int t = 0; t < 4; ++t) xs[t][tid] = x[(r0 + t) * D_DIM + tid];
    __syncthreads();
    const float bv_ = b[tid];
    float acc[4];
    #pragma unroll
    for (int i = 0; i < 4; ++i) acc[i] = xs[i][tid] + bv_;
    #pragma unroll 4
    for (int e = 0; e < D_DIM; ++e) {
        const float w = W[e * D_DIM + tid];
        #pragma unroll
        for (int i = 0; i < 4; ++i) acc[i] += xs[i][e] * w;
    }
    #pragma unroll
    for (int i = 0; i < 4; ++i) y[(r0 + i) * D_DIM + tid] = acc[i];
}

// ---------------------------------------------------------------------------
// Final linear with partial-sum fusion: x = sum_c po[c]; out = x + x@W + b
// ---------------------------------------------------------------------------
__global__ __launch_bounds__(256) void linres_sum(
    const float* __restrict__ po, const float* __restrict__ W,
    const float* __restrict__ b, float* __restrict__ y)
{
    __shared__ float xs[4][D_DIM];
    const int tid = threadIdx.x;
    const int r0  = blockIdx.x * 4;
    #pragma unroll
    for (int t = 0; t < 4; ++t) {
        float s = 0.f;
        #pragma unroll
        for (int c = 0; c < NCH; ++c)
            s += po[(size_t)c * SLICE + (r0 + t) * D_DIM + tid];
        xs[t][tid] = s;
    }
    __syncthreads();
    const float bv_ = b[tid];
    float acc[4];
    #pragma unroll
    for (int i = 0; i < 4; ++i) acc[i] = xs[i][tid] + bv_;
    #pragma unroll 4
    for (int e = 0; e < D_DIM; ++e) {
        const float w = W[e * D_DIM + tid];
        #pragma unroll
        for (int i = 0; i < 4; ++i) acc[i] += xs[i][e] * w;
    }
    #pragma unroll
    for (int i = 0; i < 4; ++i) y[(r0 + i) * D_DIM + tid] = acc[i];
}

// ---------------------------------------------------------------------------
// Stage 64x256 fp16 q tile into fragment-major LDS (R3/R7/R11-proven):
// fb = mt*8+kk; slot = quad*16+l16; addr16 = fb*64 + slot. Conflict-free.
// ---------------------------------------------------------------------------
__device__ __forceinline__ void stage_q(const _Float16* __restrict__ qh,
                                        _Float16* __restrict__ Afrag,
                                        int sq0, int tid)
{
    const int i   = tid & 63;   // row within tile
    const int qtr = tid >> 6;   // e-quarter (64 elems)
    const int mt = i >> 4, l16 = i & 15;
    const half8* src = (const half8*)(qh + (size_t)(sq0 + i) * D_DIM + qtr * 64);
    #pragma unroll
    for (int u = 0; u < 8; ++u) {
        const int eb   = qtr * 8 + u;           // e-block (8 halfs) 0..31
        const int kk   = eb >> 2, quad = eb & 3;
        const int addr16 = (mt * 8 + kk) * 64 + quad * 16 + l16;
        *(half8*)(Afrag + addr16 * 8) = src[u];
    }
}

// Same layout for a 32-row tile (mt in {0,1}), 4 half8 per thread (R8-proven).
__device__ __forceinline__ void stage_q32(const _Float16* __restrict__ qh,
                                          _Float16* __restrict__ Afrag,
                                          int sq0, int tid)
{
    const int i   = tid & 31;   // row within tile
    const int oct = tid >> 5;   // e-eighth (32 halfs)
    const int mt = i >> 4, l16 = i & 15;
    const half8* src = (const half8*)(qh + (size_t)(sq0 + i) * D_DIM);
    #pragma unroll
    for (int u = 0; u < 4; ++u) {
        const int eb   = oct * 4 + u;           // e-block (8 halfs) 0..31
        const int kk   = eb >> 2, quad = eb & 3;
        const int addr16 = (mt * 8 + kk) * 64 + quad * 16 + l16;
        *(half8*)(Afrag + addr16 * 8) = src[eb];
    }
}

// ---------------------------------------------------------------------------
// Stats: per-(sk,d) tile-partial (max, sum |L| e^(L-max)) over 64 sq rows.
// Grid (8 sq-tiles, 4 d-quarters, 16 sk-chunks of 32) = 512 blocks = 2/CU.
// __launch_bounds__(256,2): 256-VGPR budget — the ONLY spill-free point
// (R15: (256,4)'s 128-VGPR cap spilled wl -> 588 MB scratch FETCH).
// Latency hiding via ILP: 4 sk batched per inner pass — wl/af shared,
// 16 independent MFMAs per kk. kk loop FULLY unrolled (wl stays in VGPRs).
// ---------------------------------------------------------------------------
__global__ __launch_bounds__(256, 2) void stats_mfma(
    const _Float16* __restrict__ qh, const _Float16* __restrict__ kh,
    const _Float16* __restrict__ WlhT, const float* __restrict__ bl,
    float* __restrict__ pm, float* __restrict__ ps)
{
    __shared__ _Float16 Afrag[32 * 64 * 8];   // 32 KB

    const int tid  = threadIdx.x;
    const int lane = tid & 63, wave = tid >> 6;
    const int quad = lane >> 4, l16 = lane & 15;
    const int sqt  = blockIdx.x, sq0 = sqt * 64;
    const int dw   = blockIdx.y * 64 + wave * 16;
    const int sk0  = blockIdx.z * 32;
    const int d    = dw + l16;

    stage_q(qh, Afrag, sq0, tid);

    half8 wl[8];
    #pragma unroll
    for (int kk = 0; kk < 8; ++kk)
        wl[kk] = *(const half8*)(WlhT + (size_t)d * D_DIM + kk * 32 + quad * 8);
    const float bl_r = bl[d];

    __syncthreads();

    #pragma unroll 1
    for (int s4 = 0; s4 < 32; s4 += 4) {
        const int sk = sk0 + s4;
        floatx4 acc[4][4];   // [sj][mt]
        #pragma unroll
        for (int sj = 0; sj < 4; ++sj)
            #pragma unroll
            for (int mt = 0; mt < 4; ++mt)
                acc[sj][mt] = (floatx4){0.f, 0.f, 0.f, 0.f};

        #pragma unroll
        for (int kk = 0; kk < 8; ++kk) {
            half8 bf[4];
            #pragma unroll
            for (int sj = 0; sj < 4; ++sj) {
                const half8 k8 = *(const half8*)(kh + (size_t)(sk + sj) * D_DIM + kk * 32 + quad * 8);
                bf[sj] = wl[kk] * k8;
            }
            half8 af[4];
            #pragma unroll
            for (int mt = 0; mt < 4; ++mt)
                af[mt] = *(const half8*)(Afrag + ((mt * 8 + kk) * 64 + lane) * 8);
            #pragma unroll
            for (int mt = 0; mt < 4; ++mt)
                #pragma unroll
                for (int sj = 0; sj < 4; ++sj)
                    acc[sj][mt] = __builtin_amdgcn_mfma_f32_16x16x32_f16(
                        af[mt], bf[sj], acc[sj][mt], 0, 0, 0);
        }

        #pragma unroll
        for (int sj = 0; sj < 4; ++sj) {
            float tmax = -1e30f;
            #pragma unroll
            for (int mt = 0; mt < 4; ++mt)
                #pragma unroll
                for (int r = 0; r < 4; ++r)
                    tmax = fmaxf(tmax, acc[sj][mt][r] + bl_r);
            float tsum = 0.f;
            #pragma unroll
            for (int mt = 0; mt < 4; ++mt)
                #pragma unroll
                for (int r = 0; r < 4; ++r) {
                    const float L = acc[sj][mt][r] + bl_r;
                    tsum += fabsf(L) * __expf(L - tmax);
                }

            float m = tmax, ss = tsum;
            #pragma unroll
            for (int mask = 16; mask <= 32; mask <<= 1) {
                float m2 = __shfl_xor(m, mask, 64);
                float s2 = __shfl_xor(ss, mask, 64);
                float M  = fmaxf(m, m2);
                ss = ss * __expf(m - M) + s2 * __expf(m2 - M);
                m = M;
            }
            if (quad == 0) {
                pm[((size_t)sqt * S_LEN + sk + sj) * D_DIM + d] = m;
                ps[((size_t)sqt * S_LEN + sk + sj) * D_DIM + d] = ss;
            }
        }
    }
}

// ---------------------------------------------------------------------------
// Merge the 8 sq-tile partials -> mbuf, sbuf  (R3/R7/R11-proven)
// ---------------------------------------------------------------------------
__global__ __launch_bounds__(256) void reduce_ms(
    const float* __restrict__ pm, const float* __restrict__ ps,
    float* __restrict__ mbuf, float* __restrict__ sbuf)
{
    const int idx = blockIdx.x * 256 + threadIdx.x;   // (sk,d), 131072 total
    float m = pm[idx], ss = ps[idx];
    #pragma unroll
    for (int t = 1; t < 8; ++t) {
        const float m2 = pm[t * SLICE + idx];
        const float s2 = ps[t * SLICE + idx];
        const float M  = fmaxf(m, m2);
        ss = ss * __expf(m - M) + s2 * __expf(m2 - M);
        m = M;
    }
    mbuf[idx] = m;
    sbuf[idx] = ss;
}

// ---------------------------------------------------------------------------
// Accum: recompute L, p = L e^(L-m)/(S+1); o += v[sk,d]*p over 64 sk;
// PLAIN stores of the 32x64 fp32 partial tile to po[chunk] (no atomics).
// Grid (16 sq-tiles of 32, 4 d-quarters, 8 sk-chunks of 64) = 512 = 2/CU.
// 4-sk batched inner loop (ILP); kk FULLY unrolled; launch_bounds(256,2).
// ---------------------------------------------------------------------------
__global__ __launch_bounds__(256, 2) void accum_mfma(
    const _Float16* __restrict__ qh, const _Float16* __restrict__ kh,
    const _Float16* __restrict__ WlhT, const float* __restrict__ bl,
    const float* __restrict__ mbuf, const float* __restrict__ sbuf,
    const float* __restrict__ vbuf, float* __restrict__ po)
{
    __shared__ _Float16 Afrag[16 * 64 * 8];   // 16 KB

    const int tid  = threadIdx.x;
    const int lane = tid & 63, wave = tid >> 6;
    const int quad = lane >> 4, l16 = lane & 15;
    const int sq0  = blockIdx.x * 32;
    const int dw   = blockIdx.y * 64 + wave * 16;
    const int chunk = blockIdx.z;
    const int sk0  = chunk * 64;
    const int d    = dw + l16;

    stage_q32(qh, Afrag, sq0, tid);

    half8 wl[8];
    #pragma unroll
    for (int kk = 0; kk < 8; ++kk)
        wl[kk] = *(const half8*)(WlhT + (size_t)d * D_DIM + kk * 32 + quad * 8);
    const float bl_r = bl[d];

    floatx4 o[2];
    o[0] = (floatx4){0.f, 0.f, 0.f, 0.f};
    o[1] = (floatx4){0.f, 0.f, 0.f, 0.f};

    __syncthreads();

    #pragma unroll 1
    for (int s4 = 0; s4 < 64; s4 += 4) {
        const int sk = sk0 + s4;
        floatx4 acc[4][2];   // [sj][mt]
        #pragma unroll
        for (int sj = 0; sj < 4; ++sj) {
            acc[sj][0] = (floatx4){0.f, 0.f, 0.f, 0.f};
            acc[sj][1] = (floatx4){0.f, 0.f, 0.f, 0.f};
        }

        #pragma unroll
        for (int kk = 0; kk < 8; ++kk) {
            half8 bf[4];
            #pragma unroll
            for (int sj = 0; sj < 4; ++sj) {
                const half8 k8 = *(const half8*)(kh + (size_t)(sk + sj) * D_DIM + kk * 32 + quad * 8);
                bf[sj] = wl[kk] * k8;
            }
            const half8 af0 = *(const half8*)(Afrag + ((0 * 8 + kk) * 64 + lane) * 8);
            const half8 af1 = *(const half8*)(Afrag + ((1 * 8 + kk) * 64 + lane) * 8);
            #pragma unroll
            for (int sj = 0; sj < 4; ++sj) {
                acc[sj][0] = __builtin_amdgcn_mfma_f32_16x16x32_f16(af0, bf[sj], acc[sj][0], 0, 0, 0);
                acc[sj][1] = __builtin_amdgcn_mfma_f32_16x16x32_f16(af1, bf[sj], acc[sj][1], 0, 0, 0);
            }
        }

        #pragma unroll
        for (int sj = 0; sj < 4; ++sj) {
            const int sks = sk + sj;
            const float m_r = mbuf[(size_t)sks * D_DIM + d];
            const float inv = 1.0f / (sbuf[(size_t)sks * D_DIM + d] + 1.0f);
            const float vv  = vbuf[(size_t)sks * D_DIM + d];
            #pragma unroll
            for (int mt = 0; mt < 2; ++mt)
                #pragma unroll
                for (int r = 0; r < 4; ++r) {
                    const float L = acc[sj][mt][r] + bl_r;
                    const float p = L * __expf(L - m_r) * inv;
                    o[mt][r] += vv * p;
                }
        }
    }

    float* dst = po + (size_t)chunk * SLICE;
    #pragma unroll
    for (int mt = 0; mt < 2; ++mt)
        #pragma unroll
        for (int r = 0; r < 4; ++r) {
            const int row = sq0 + mt * 16 + quad * 4 + r;
            dst[(size_t)row * D_DIM + d] = o[mt][r];
        }
}

// ---------------------------------------------------------------------------
extern "C" void kernel_launch(void* const* d_in, const int* in_sizes, int n_in,
                              void* d_out, int out_size, void* d_ws, size_t ws_size,
                              hipStream_t stream)
{
    const float* query = (const float*)d_in[0];
    const float* key   = (const float*)d_in[1];
    const float* value = (const float*)d_in[2];
    const float* Wk  = (const float*)d_in[3];
    const float* bk  = (const float*)d_in[4];
    const float* Wq  = (const float*)d_in[5];
    const float* bq  = (const float*)d_in[6];
    const float* Wva = (const float*)d_in[7];
    const float* bva = (const float*)d_in[8];
    const float* Wl  = (const float*)d_in[9];
    const float* bl  = (const float*)d_in[10];
    const float* Wvo = (const float*)d_in[11];
    const float* bvo = (const float*)d_in[12];

    const int MAT = SLICE;                    // 131072
    float* ws   = (float*)d_ws;
    // R11/R12-proven footprint; po (8 slices) overlays dead pm.
    float* kbuf = ws;
    float* qbuf = ws + MAT;
    float* vbuf = ws + 2 * MAT;
    float* mbuf = ws + 3 * MAT;
    float* sbuf = ws + 4 * MAT;
    _Float16* WlhT = (_Float16*)(ws + 6 * MAT);            // 128 KB
    _Float16* kh   = (_Float16*)(ws + 6 * MAT + 32768);    // 256 KB
    _Float16* qh   = kh + MAT;                             // 256 KB
    float* pm  = ws + 6 * MAT + 32768 + 2 * 65536;         // 4 MB
    float* ps  = pm + 8 * MAT;                             // 4 MB
    float* po  = pm;   // NCH*MAT floats (4 MB), pm dead after reduce_ms
    float* out = (float*)d_out;

    prep_wl<<<256, 256, 0, stream>>>(Wl, WlhT);
    linres3<<<dim3(128, 3), 256, 0, stream>>>(key, Wk, bk, kbuf,
                                              query, Wq, bq, qbuf,
                                              value, Wva, bva, vbuf);
    cvt_fp16<<<128, 256, 0, stream>>>(kbuf, qbuf, kh, qh);

    stats_mfma<<<dim3(8, 4, 16), 256, 0, stream>>>(qh, kh, WlhT, bl, pm, ps);
    reduce_ms<<<512, 256, 0, stream>>>(pm, ps, mbuf, sbuf);
    accum_mfma<<<dim3(16, 4, 8), 256, 0, stream>>>(qh, kh, WlhT, bl,
                                                   mbuf, sbuf, vbuf, po);

    linres_sum<<<128, 256, 0, stream>>>(po, Wvo, bvo, out);
}

// Round 17
// 233.030 us; speedup vs baseline: 1.8117x; 1.2845x over previous
//
#include <hip/hip_runtime.h>
#include <math.h>

#define S_LEN 512
#define D_DIM 256
#define SLICE (S_LEN * D_DIM)   // 131072

typedef _Float16 half8  __attribute__((ext_vector_type(8)));
typedef _Float16 half4v __attribute__((ext_vector_type(4)));
typedef float   floatx4 __attribute__((ext_vector_type(4)));

// ---------------------------------------------------------------------------
// WlhT[d][e] = fp16(Wl[e][d] + (e==d))     (raw + raw@Wl == raw@(I+Wl))
// ---------------------------------------------------------------------------
__global__ __launch_bounds__(256) void prep_wl(const float* __restrict__ Wl,
                                               _Float16* __restrict__ WlhT)
{
    const int d = blockIdx.x, e = threadIdx.x;
    float v = Wl[e * D_DIM + d] + (e == d ? 1.0f : 0.0f);
    WlhT[d * D_DIM + e] = (_Float16)v;
}

// ---------------------------------------------------------------------------
// fp32 -> fp16 copies of k and q (post-linres)
// ---------------------------------------------------------------------------
__global__ __launch_bounds__(256) void cvt_fp16(const float* __restrict__ kf,
                                                const float* __restrict__ qf,
                                                _Float16* __restrict__ kh,
                                                _Float16* __restrict__ qh)
{
    const int i = (blockIdx.x * 256 + threadIdx.x) * 4;
    float4 a = *(const float4*)(kf + i);
    float4 b = *(const float4*)(qf + i);
    half4v ah = { (_Float16)a.x, (_Float16)a.y, (_Float16)a.z, (_Float16)a.w };
    half4v bh = { (_Float16)b.x, (_Float16)b.y, (_Float16)b.z, (_Float16)b.w };
    *(half4v*)(kh + i) = ah;
    *(half4v*)(qh + i) = bh;
}

// ---------------------------------------------------------------------------
// y = x + x@W + b  for [512,256]@[256,256]; 4 rows per block (fp32, small).
// ---------------------------------------------------------------------------
__global__ __launch_bounds__(256) void linres3(
    const float* __restrict__ xk, const float* __restrict__ Wk,
    const float* __restrict__ bk, float* __restrict__ yk,
    const float* __restrict__ xq, const float* __restrict__ Wq,
    const float* __restrict__ bq, float* __restrict__ yq,
    const float* __restrict__ xv, const float* __restrict__ Wv,
    const float* __restrict__ bv, float* __restrict__ yv)
{
    __shared__ float xs[4][D_DIM];
    const int r0 = blockIdx.x * 4;
    const int sel = blockIdx.y;
    const float* x = sel == 0 ? xk : (sel == 1 ? xq : xv);
    const float* W = sel == 0 ? Wk : (sel == 1 ? Wq : Wv);
    const float* b = sel == 0 ? bk : (sel == 1 ? bq : bv);
    float*       y = sel == 0 ? yk : (sel == 1 ? yq : yv);

    const int tid = threadIdx.x;
    #pragma unroll
    for (int t = 0; t < 4; ++t) xs[t][tid] = x[(r0 + t) * D_DIM + tid];
    __syncthreads();
    const float bv_ = b[tid];
    float acc[4];
    #pragma unroll
    for (int i = 0; i < 4; ++i) acc[i] = xs[i][tid] + bv_;
    #pragma unroll 4
    for (int e = 0; e < D_DIM; ++e) {
        const float w = W[e * D_DIM + tid];
        #pragma unroll
        for (int i = 0; i < 4; ++i) acc[i] += xs[i][e] * w;
    }
    #pragma unroll
    for (int i = 0; i < 4; ++i) y[(r0 + i) * D_DIM + tid] = acc[i];
}

// ---------------------------------------------------------------------------
// Final linear with partial-sum fusion: x = sum_c po[c]; out = x + x@W + b
// ---------------------------------------------------------------------------
__global__ __launch_bounds__(256) void linres_sum(
    const float* __restrict__ po, const float* __restrict__ W,
    const float* __restrict__ b, float* __restrict__ y)
{
    __shared__ float xs[4][D_DIM];
    const int tid = threadIdx.x;
    const int r0  = blockIdx.x * 4;
    #pragma unroll
    for (int t = 0; t < 4; ++t) {
        float s = 0.f;
        #pragma unroll
        for (int c = 0; c < 16; ++c)
            s += po[(size_t)c * SLICE + (r0 + t) * D_DIM + tid];
        xs[t][tid] = s;
    }
    __syncthreads();
    const float bv_ = b[tid];
    float acc[4];
    #pragma unroll
    for (int i = 0; i < 4; ++i) acc[i] = xs[i][tid] + bv_;
    #pragma unroll 4
    for (int e = 0; e < D_DIM; ++e) {
        const float w = W[e * D_DIM + tid];
        #pragma unroll
        for (int i = 0; i < 4; ++i) acc[i] += xs[i][e] * w;
    }
    #pragma unroll
    for (int i = 0; i < 4; ++i) y[(r0 + i) * D_DIM + tid] = acc[i];
}

// ---------------------------------------------------------------------------
// Stage 64x256 fp16 q tile into fragment-major LDS (R3/R7/R11-proven).
// ---------------------------------------------------------------------------
__device__ __forceinline__ void stage_q(const _Float16* __restrict__ qh,
                                        _Float16* __restrict__ Afrag,
                                        int sq0, int tid)
{
    const int i   = tid & 63;
    const int qtr = tid >> 6;
    const int mt = i >> 4, l16 = i & 15;
    const half8* src = (const half8*)(qh + (size_t)(sq0 + i) * D_DIM + qtr * 64);
    #pragma unroll
    for (int u = 0; u < 8; ++u) {
        const int eb   = qtr * 8 + u;
        const int kk   = eb >> 2, quad = eb & 3;
        const int addr16 = (mt * 8 + kk) * 64 + quad * 16 + l16;
        *(half8*)(Afrag + addr16 * 8) = src[u];
    }
}

// Same layout for a 32-row tile (R8-proven).
__device__ __forceinline__ void stage_q32(const _Float16* __restrict__ qh,
                                          _Float16* __restrict__ Afrag,
                                          int sq0, int tid)
{
    const int i   = tid & 31;
    const int oct = tid >> 5;
    const int mt = i >> 4, l16 = i & 15;
    const half8* src = (const half8*)(qh + (size_t)(sq0 + i) * D_DIM);
    #pragma unroll
    for (int u = 0; u < 4; ++u) {
        const int eb   = oct * 4 + u;
        const int kk   = eb >> 2, quad = eb & 3;
        const int addr16 = (mt * 8 + kk) * 64 + quad * 16 + l16;
        *(half8*)(Afrag + addr16 * 8) = src[eb];
    }
}

// ---------------------------------------------------------------------------
// Prefetch helpers — compile-time-constant indexing only (scratch-demotion
// safe: R7-R9 bug). kb holds one sk row's 8 k8 fragments (32 VGPRs).
// ---------------------------------------------------------------------------
__device__ __forceinline__ void load_k8(const _Float16* __restrict__ kh,
                                        int sk, int quad, half8 (&kb)[8])
{
    #pragma unroll
    for (int kk = 0; kk < 8; ++kk)
        kb[kk] = *(const half8*)(kh + (size_t)sk * D_DIM + kk * 32 + quad * 8);
}

__device__ __forceinline__ void load_c2(const float2* __restrict__ msv,
                                        int sk, int dw, int l16, float2 (&c)[2])
{
    #pragma unroll
    for (int nt = 0; nt < 2; ++nt)
        c[nt] = msv[((size_t)sk << 8) + dw + nt * 16 + l16];
}

// ---------------------------------------------------------------------------
// Stats per-sk body (identical math to R12): 32 MFMAs + online max/abs-exp.
// ---------------------------------------------------------------------------
__device__ __forceinline__ void stats_body(
    const _Float16* __restrict__ Afrag, const half8 (&kb)[8],
    const half8 (&wl)[2][8], const float (&bl_r)[2],
    int lane, int dw, int l16, int sqt, int sk, int quad,
    float* __restrict__ pm, float* __restrict__ ps)
{
    floatx4 acc[4][2];
    #pragma unroll
    for (int mt = 0; mt < 4; ++mt)
        #pragma unroll
        for (int nt = 0; nt < 2; ++nt)
            acc[mt][nt] = (floatx4){0.f, 0.f, 0.f, 0.f};

    #pragma unroll
    for (int kk = 0; kk < 8; ++kk) {
        half8 af[4], bf[2];
        #pragma unroll
        for (int mt = 0; mt < 4; ++mt)
            af[mt] = *(const half8*)(Afrag + ((mt * 8 + kk) * 64 + lane) * 8);
        #pragma unroll
        for (int nt = 0; nt < 2; ++nt)
            bf[nt] = wl[nt][kk] * kb[kk];
        #pragma unroll
        for (int mt = 0; mt < 4; ++mt)
            #pragma unroll
            for (int nt = 0; nt < 2; ++nt)
                acc[mt][nt] = __builtin_amdgcn_mfma_f32_16x16x32_f16(
                    af[mt], bf[nt], acc[mt][nt], 0, 0, 0);
    }

    #pragma unroll
    for (int nt = 0; nt < 2; ++nt) {
        float Lv[4][4];
        float tmax = -1e30f;
        #pragma unroll
        for (int mt = 0; mt < 4; ++mt)
            #pragma unroll
            for (int r = 0; r < 4; ++r) {
                const float L = acc[mt][nt][r] + bl_r[nt];
                Lv[mt][r] = L;
                tmax = fmaxf(tmax, L);
            }
        float tsum = 0.f;
        #pragma unroll
        for (int mt = 0; mt < 4; ++mt)
            #pragma unroll
            for (int r = 0; r < 4; ++r)
                tsum += fabsf(Lv[mt][r]) * __expf(Lv[mt][r] - tmax);

        float m = tmax, ss = tsum;
        #pragma unroll
        for (int mask = 16; mask <= 32; mask <<= 1) {
            float m2 = __shfl_xor(m, mask, 64);
            float s2 = __shfl_xor(ss, mask, 64);
            float M  = fmaxf(m, m2);
            ss = ss * __expf(m - M) + s2 * __expf(m2 - M);
            m = M;
        }
        if (quad == 0) {
            const int d = dw + nt * 16 + l16;
            pm[((size_t)sqt * S_LEN + sk) * D_DIM + d] = m;
            ps[((size_t)sqt * S_LEN + sk) * D_DIM + d] = ss;
        }
    }
}

// ---------------------------------------------------------------------------
// Stats: R12 config (grid (8,2,32), chunk 16, nt=2/mt=4, launch_bounds(256,2))
// + register ping-pong prefetch of next-sk k8 fragments: loads for s+1 issue
// before s's MFMA+epilogue (~500 cyc of cover), removing the ~200-cyc L2 wait
// that caused R12's 44% stall.
// ---------------------------------------------------------------------------
__global__ __launch_bounds__(256, 2) void stats_mfma(
    const _Float16* __restrict__ qh, const _Float16* __restrict__ kh,
    const _Float16* __restrict__ WlhT, const float* __restrict__ bl,
    float* __restrict__ pm, float* __restrict__ ps)
{
    __shared__ _Float16 Afrag[32 * 64 * 8];   // 32 KB

    const int tid  = threadIdx.x;
    const int lane = tid & 63, wave = tid >> 6;
    const int quad = lane >> 4, l16 = lane & 15;
    const int sqt  = blockIdx.x, sq0 = sqt * 64;
    const int dw   = blockIdx.y * 128 + wave * 32;
    const int sk0  = blockIdx.z * 16;

    stage_q(qh, Afrag, sq0, tid);

    half8 wl[2][8];
    #pragma unroll
    for (int nt = 0; nt < 2; ++nt) {
        const int d = dw + nt * 16 + l16;
        #pragma unroll
        for (int kk = 0; kk < 8; ++kk)
            wl[nt][kk] = *(const half8*)(WlhT + (size_t)d * D_DIM + kk * 32 + quad * 8);
    }
    float bl_r[2];
    #pragma unroll
    for (int nt = 0; nt < 2; ++nt)
        bl_r[nt] = bl[dw + nt * 16 + l16];

    __syncthreads();

    half8 kA[8], kB[8];
    load_k8(kh, sk0, quad, kA);

    #pragma unroll 1
    for (int s2 = 0; s2 < 16; s2 += 2) {
        load_k8(kh, sk0 + s2 + 1, quad, kB);          // in flight during body A
        stats_body(Afrag, kA, wl, bl_r, lane, dw, l16, sqt, sk0 + s2, quad, pm, ps);
        const int sn = (s2 + 2 < 16) ? s2 + 2 : 15;   // tail: harmless reload
        load_k8(kh, sk0 + sn, quad, kA);              // in flight during body B
        stats_body(Afrag, kB, wl, bl_r, lane, dw, l16, sqt, sk0 + s2 + 1, quad, pm, ps);
    }
}

// ---------------------------------------------------------------------------
// Merge the 8 sq-tile partials; fold epilogue constants (R9-proven algebra):
// msv[sk,d] = { bl - m,  v/(S+1) }
// ---------------------------------------------------------------------------
__global__ __launch_bounds__(256) void reduce_ms(
    const float* __restrict__ pm, const float* __restrict__ ps,
    const float* __restrict__ vbuf, const float* __restrict__ bl,
    float2* __restrict__ msv)
{
    const int idx = blockIdx.x * 256 + threadIdx.x;   // sk*256 + d
    float m = pm[idx], ss = ps[idx];
    #pragma unroll
    for (int t = 1; t < 8; ++t) {
        const float m2 = pm[t * SLICE + idx];
        const float s2 = ps[t * SLICE + idx];
        const float M  = fmaxf(m, m2);
        ss = ss * __expf(m - M) + s2 * __expf(m2 - M);
        m = M;
    }
    msv[idx] = make_float2(bl[idx & 255] - m, vbuf[idx] / (ss + 1.0f));
}

// ---------------------------------------------------------------------------
// Accum per-sk body (R12 tile, R9-folded epilogue): 16 MFMAs + o update.
// ---------------------------------------------------------------------------
__device__ __forceinline__ void accum_body(
    const _Float16* __restrict__ Afrag, const half8 (&kb)[8],
    const half8 (&wl)[2][8], const float (&bl_r)[2], const float2 (&c)[2],
    int lane, floatx4 (&o)[2][2])
{
    floatx4 acc[2][2];
    #pragma unroll
    for (int mt = 0; mt < 2; ++mt)
        #pragma unroll
        for (int nt = 0; nt < 2; ++nt)
            acc[mt][nt] = (floatx4){0.f, 0.f, 0.f, 0.f};

    #pragma unroll
    for (int kk = 0; kk < 8; ++kk) {
        half8 af[2], bf[2];
        #pragma unroll
        for (int mt = 0; mt < 2; ++mt)
            af[mt] = *(const half8*)(Afrag + ((mt * 8 + kk) * 64 + lane) * 8);
        #pragma unroll
        for (int nt = 0; nt < 2; ++nt)
            bf[nt] = wl[nt][kk] * kb[kk];
        #pragma unroll
        for (int mt = 0; mt < 2; ++mt)
            #pragma unroll
            for (int nt = 0; nt < 2; ++nt)
                acc[mt][nt] = __builtin_amdgcn_mfma_f32_16x16x32_f16(
                    af[mt], bf[nt], acc[mt][nt], 0, 0, 0);
    }

    #pragma unroll
    for (int nt = 0; nt < 2; ++nt)
        #pragma unroll
        for (int mt = 0; mt < 2; ++mt)
            #pragma unroll
            for (int r = 0; r < 4; ++r) {
                const float Lp = acc[mt][nt][r];
                const float e  = __expf(Lp + c[nt].x);       // e^(L-m)
                const float u  = (Lp + bl_r[nt]) * c[nt].y;  // L * v/(S+1)
                o[mt][nt][r] = fmaf(u, e, o[mt][nt][r]);
            }
}

// ---------------------------------------------------------------------------
// Accum: R12 config (grid (16,2,16), chunk 32, plain stores to po[chunk]) +
// ping-pong prefetch of k8 and the folded msv constants.
// ---------------------------------------------------------------------------
__global__ __launch_bounds__(256, 2) void accum_mfma(
    const _Float16* __restrict__ qh, const _Float16* __restrict__ kh,
    const _Float16* __restrict__ WlhT, const float* __restrict__ bl,
    const float2* __restrict__ msv, float* __restrict__ po)
{
    __shared__ _Float16 Afrag[16 * 64 * 8];   // 16 KB

    const int tid  = threadIdx.x;
    const int lane = tid & 63, wave = tid >> 6;
    const int quad = lane >> 4, l16 = lane & 15;
    const int sq0  = blockIdx.x * 32;
    const int dw   = blockIdx.y * 128 + wave * 32;
    const int chunk = blockIdx.z;
    const int sk0  = chunk * 32;

    stage_q32(qh, Afrag, sq0, tid);

    half8 wl[2][8];
    #pragma unroll
    for (int nt = 0; nt < 2; ++nt) {
        const int d = dw + nt * 16 + l16;
        #pragma unroll
        for (int kk = 0; kk < 8; ++kk)
            wl[nt][kk] = *(const half8*)(WlhT + (size_t)d * D_DIM + kk * 32 + quad * 8);
    }
    float bl_r[2];
    #pragma unroll
    for (int nt = 0; nt < 2; ++nt)
        bl_r[nt] = bl[dw + nt * 16 + l16];

    floatx4 o[2][2];
    #pragma unroll
    for (int mt = 0; mt < 2; ++mt)
        #pragma unroll
        for (int nt = 0; nt < 2; ++nt)
            o[mt][nt] = (floatx4){0.f, 0.f, 0.f, 0.f};

    __syncthreads();

    half8 kA[8], kB[8];
    float2 cA[2], cB[2];
    load_k8(kh, sk0, quad, kA);
    load_c2(msv, sk0, dw, l16, cA);

    #pragma unroll 1
    for (int s2 = 0; s2 < 32; s2 += 2) {
        load_k8(kh, sk0 + s2 + 1, quad, kB);
        load_c2(msv, sk0 + s2 + 1, dw, l16, cB);
        accum_body(Afrag, kA, wl, bl_r, cA, lane, o);
        const int sn = (s2 + 2 < 32) ? s2 + 2 : 31;
        load_k8(kh, sk0 + sn, quad, kA);
        load_c2(msv, sk0 + sn, dw, l16, cA);
        accum_body(Afrag, kB, wl, bl_r, cB, lane, o);
    }

    float* dst = po + (size_t)chunk * SLICE;
    #pragma unroll
    for (int mt = 0; mt < 2; ++mt)
        #pragma unroll
        for (int nt = 0; nt < 2; ++nt)
            #pragma unroll
            for (int r = 0; r < 4; ++r) {
                const int row = sq0 + mt * 16 + quad * 4 + r;
                const int col = dw + nt * 16 + l16;
                dst[(size_t)row * D_DIM + col] = o[mt][nt][r];
            }
}

// ---------------------------------------------------------------------------
extern "C" void kernel_launch(void* const* d_in, const int* in_sizes, int n_in,
                              void* d_out, int out_size, void* d_ws, size_t ws_size,
                              hipStream_t stream)
{
    const float* query = (const float*)d_in[0];
    const float* key   = (const float*)d_in[1];
    const float* value = (const float*)d_in[2];
    const float* Wk  = (const float*)d_in[3];
    const float* bk  = (const float*)d_in[4];
    const float* Wq  = (const float*)d_in[5];
    const float* bq  = (const float*)d_in[6];
    const float* Wva = (const float*)d_in[7];
    const float* bva = (const float*)d_in[8];
    const float* Wl  = (const float*)d_in[9];
    const float* bl  = (const float*)d_in[10];
    const float* Wvo = (const float*)d_in[11];
    const float* bvo = (const float*)d_in[12];

    const int MAT = SLICE;                    // 131072
    float* ws   = (float*)d_ws;
    // R12-proven footprint. msv (float2, SLICE) occupies the old mbuf+sbuf
    // slots; po (16 slices, 8 MB) overlays pm+ps (dead after reduce_ms).
    float* kbuf = ws;
    float* qbuf = ws + MAT;
    float* vbuf = ws + 2 * MAT;
    float2* msv = (float2*)(ws + 3 * MAT);                 // 2 slots = SLICE f2
    _Float16* WlhT = (_Float16*)(ws + 6 * MAT);            // 128 KB
    _Float16* kh   = (_Float16*)(ws + 6 * MAT + 32768);    // 256 KB
    _Float16* qh   = kh + MAT;                             // 256 KB
    float* pm  = ws + 6 * MAT + 32768 + 2 * 65536;         // 4 MB
    float* ps  = pm + 8 * MAT;                             // 4 MB
    float* po  = pm;   // 16*MAT floats (8 MB)
    float* out = (float*)d_out;

    prep_wl<<<256, 256, 0, stream>>>(Wl, WlhT);
    linres3<<<dim3(128, 3), 256, 0, stream>>>(key, Wk, bk, kbuf,
                                              query, Wq, bq, qbuf,
                                              value, Wva, bva, vbuf);
    cvt_fp16<<<128, 256, 0, stream>>>(kbuf, qbuf, kh, qh);

    stats_mfma<<<dim3(8, 2, 32), 256, 0, stream>>>(qh, kh, WlhT, bl, pm, ps);
    reduce_ms<<<512, 256, 0, stream>>>(pm, ps, vbuf, bl, msv);
    accum_mfma<<<dim3(16, 2, 16), 256, 0, stream>>>(qh, kh, WlhT, bl, msv, po);

    linres_sum<<<128, 256, 0, stream>>>(po, Wvo, bvo, out);
}

// Round 18
// 232.716 us; speedup vs baseline: 1.8142x; 1.0013x over previous
//
#include <hip/hip_runtime.h>
#include <math.h>

#define S_LEN 512
#define D_DIM 256
#define SLICE (S_LEN * D_DIM)   // 131072

typedef _Float16 half8  __attribute__((ext_vector_type(8)));
typedef _Float16 half4v __attribute__((ext_vector_type(4)));
typedef float   floatx4 __attribute__((ext_vector_type(4)));

// ---------------------------------------------------------------------------
// WlhT[d][e] = fp16(Wl[e][d] + (e==d))     (raw + raw@Wl == raw@(I+Wl))
// ---------------------------------------------------------------------------
__global__ __launch_bounds__(256) void prep_wl(const float* __restrict__ Wl,
                                               _Float16* __restrict__ WlhT)
{
    const int d = blockIdx.x, e = threadIdx.x;
    float v = Wl[e * D_DIM + d] + (e == d ? 1.0f : 0.0f);
    WlhT[d * D_DIM + e] = (_Float16)v;
}

// ---------------------------------------------------------------------------
// fp32 -> fp16 copies of k and q (post-linres)
// ---------------------------------------------------------------------------
__global__ __launch_bounds__(256) void cvt_fp16(const float* __restrict__ kf,
                                                const float* __restrict__ qf,
                                                _Float16* __restrict__ kh,
                                                _Float16* __restrict__ qh)
{
    const int i = (blockIdx.x * 256 + threadIdx.x) * 4;
    float4 a = *(const float4*)(kf + i);
    float4 b = *(const float4*)(qf + i);
    half4v ah = { (_Float16)a.x, (_Float16)a.y, (_Float16)a.z, (_Float16)a.w };
    half4v bh = { (_Float16)b.x, (_Float16)b.y, (_Float16)b.z, (_Float16)b.w };
    *(half4v*)(kh + i) = ah;
    *(half4v*)(qh + i) = bh;
}

// ---------------------------------------------------------------------------
// y = x + x@W + b  for [512,256]@[256,256]; 4 rows per block (fp32, small).
// ---------------------------------------------------------------------------
__global__ __launch_bounds__(256) void linres3(
    const float* __restrict__ xk, const float* __restrict__ Wk,
    const float* __restrict__ bk, float* __restrict__ yk,
    const float* __restrict__ xq, const float* __restrict__ Wq,
    const float* __restrict__ bq, float* __restrict__ yq,
    const float* __restrict__ xv, const float* __restrict__ Wv,
    const float* __restrict__ bv, float* __restrict__ yv)
{
    __shared__ float xs[4][D_DIM];
    const int r0 = blockIdx.x * 4;
    const int sel = blockIdx.y;
    const float* x = sel == 0 ? xk : (sel == 1 ? xq : xv);
    const float* W = sel == 0 ? Wk : (sel == 1 ? Wq : Wv);
    const float* b = sel == 0 ? bk : (sel == 1 ? bq : bv);
    float*       y = sel == 0 ? yk : (sel == 1 ? yq : yv);

    const int tid = threadIdx.x;
    #pragma unroll
    for (int t = 0; t < 4; ++t) xs[t][tid] = x[(r0 + t) * D_DIM + tid];
    __syncthreads();
    const float bv_ = b[tid];
    float acc[4];
    #pragma unroll
    for (int i = 0; i < 4; ++i) acc[i] = xs[i][tid] + bv_;
    #pragma unroll 4
    for (int e = 0; e < D_DIM; ++e) {
        const float w = W[e * D_DIM + tid];
        #pragma unroll
        for (int i = 0; i < 4; ++i) acc[i] += xs[i][e] * w;
    }
    #pragma unroll
    for (int i = 0; i < 4; ++i) y[(r0 + i) * D_DIM + tid] = acc[i];
}

// ---------------------------------------------------------------------------
// Final linear with partial-sum fusion: x = sum_c po[c]; out = x + x@W + b
// ---------------------------------------------------------------------------
__global__ __launch_bounds__(256) void linres_sum(
    const float* __restrict__ po, const float* __restrict__ W,
    const float* __restrict__ b, float* __restrict__ y)
{
    __shared__ float xs[4][D_DIM];
    const int tid = threadIdx.x;
    const int r0  = blockIdx.x * 4;
    #pragma unroll
    for (int t = 0; t < 4; ++t) {
        float s = 0.f;
        #pragma unroll
        for (int c = 0; c < 16; ++c)
            s += po[(size_t)c * SLICE + (r0 + t) * D_DIM + tid];
        xs[t][tid] = s;
    }
    __syncthreads();
    const float bv_ = b[tid];
    float acc[4];
    #pragma unroll
    for (int i = 0; i < 4; ++i) acc[i] = xs[i][tid] + bv_;
    #pragma unroll 4
    for (int e = 0; e < D_DIM; ++e) {
        const float w = W[e * D_DIM + tid];
        #pragma unroll
        for (int i = 0; i < 4; ++i) acc[i] += xs[i][e] * w;
    }
    #pragma unroll
    for (int i = 0; i < 4; ++i) y[(r0 + i) * D_DIM + tid] = acc[i];
}

// ---------------------------------------------------------------------------
// Stats: per-(sk,d) tile-partial (max, sum |L| e^(L-max)) over 64 sq rows.
// NO LDS: A-fragments (sk-invariant) live in 128 VGPRs, loaded once from
// L2 (af[mt][kk] is 16 contiguous bytes of qh). R12's inner loop spent
// 384 cyc/body on ds_read_b128 issue vs 155 cyc of MFMA — LDS-pipe-bound.
// Wave tile sq64 x d16 (mt=4, nt=1). Grid (8 slabs, 4 d-quarters, 16 chunks
// of 32 sk) = 512 = 2/CU. launch_bounds(256,2): 256-VGPR budget (spill-free
// point; (256,4) spilled in R15). kk loops FULLY unrolled (R7-R9 bug).
// ---------------------------------------------------------------------------
__global__ __launch_bounds__(256, 2) void stats_mfma(
    const _Float16* __restrict__ qh, const _Float16* __restrict__ kh,
    const _Float16* __restrict__ WlhT, const float* __restrict__ bl,
    float* __restrict__ pm, float* __restrict__ ps)
{
    const int tid  = threadIdx.x;
    const int lane = tid & 63, wave = tid >> 6;
    const int quad = lane >> 4, l16 = lane & 15;
    const int sqt  = blockIdx.x, sq0 = sqt * 64;
    const int dw   = blockIdx.y * 64 + wave * 16;
    const int sk0  = blockIdx.z * 32;
    const int d    = dw + l16;

    // A-fragments: q rows sq0+mt*16+l16, elems kk*32+quad*8 .. +7
    half8 af[4][8];
    #pragma unroll
    for (int mt = 0; mt < 4; ++mt)
        #pragma unroll
        for (int kk = 0; kk < 8; ++kk)
            af[mt][kk] = *(const half8*)(qh +
                (size_t)(sq0 + mt * 16 + l16) * D_DIM + kk * 32 + quad * 8);

    half8 wl[8];
    #pragma unroll
    for (int kk = 0; kk < 8; ++kk)
        wl[kk] = *(const half8*)(WlhT + (size_t)d * D_DIM + kk * 32 + quad * 8);
    const float bl_r = bl[d];

    #pragma unroll 1
    for (int s = 0; s < 32; ++s) {
        const int sk = sk0 + s;
        floatx4 acc[4];
        #pragma unroll
        for (int mt = 0; mt < 4; ++mt)
            acc[mt] = (floatx4){0.f, 0.f, 0.f, 0.f};

        #pragma unroll
        for (int kk = 0; kk < 8; ++kk) {
            const half8 k8 = *(const half8*)(kh + (size_t)sk * D_DIM + kk * 32 + quad * 8);
            const half8 bf = wl[kk] * k8;
            #pragma unroll
            for (int mt = 0; mt < 4; ++mt)
                acc[mt] = __builtin_amdgcn_mfma_f32_16x16x32_f16(
                    af[mt][kk], bf, acc[mt], 0, 0, 0);
        }

        // pass 1: local max (recompute L in pass 2 — no Lv array, lower pressure)
        float tmax = -1e30f;
        #pragma unroll
        for (int mt = 0; mt < 4; ++mt)
            #pragma unroll
            for (int r = 0; r < 4; ++r)
                tmax = fmaxf(tmax, acc[mt][r] + bl_r);
        float tsum = 0.f;
        #pragma unroll
        for (int mt = 0; mt < 4; ++mt)
            #pragma unroll
            for (int r = 0; r < 4; ++r) {
                const float L = acc[mt][r] + bl_r;
                tsum += fabsf(L) * __expf(L - tmax);
            }

        float m = tmax, ss = tsum;
        #pragma unroll
        for (int mask = 16; mask <= 32; mask <<= 1) {
            float m2 = __shfl_xor(m, mask, 64);
            float s2 = __shfl_xor(ss, mask, 64);
            float M  = fmaxf(m, m2);
            ss = ss * __expf(m - M) + s2 * __expf(m2 - M);
            m = M;
        }
        if (quad == 0) {
            pm[((size_t)sqt * S_LEN + sk) * D_DIM + d] = m;
            ps[((size_t)sqt * S_LEN + sk) * D_DIM + d] = ss;
        }
    }
}

// ---------------------------------------------------------------------------
// Merge the 8 sq-slab partials; fold epilogue constants (R17-validated):
// msv[sk,d] = { bl - m,  v/(S+1) }
// ---------------------------------------------------------------------------
__global__ __launch_bounds__(256) void reduce_ms(
    const float* __restrict__ pm, const float* __restrict__ ps,
    const float* __restrict__ vbuf, const float* __restrict__ bl,
    float2* __restrict__ msv)
{
    const int idx = blockIdx.x * 256 + threadIdx.x;   // sk*256 + d
    float m = pm[idx], ss = ps[idx];
    #pragma unroll
    for (int t = 1; t < 8; ++t) {
        const float m2 = pm[t * SLICE + idx];
        const float s2 = ps[t * SLICE + idx];
        const float M  = fmaxf(m, m2);
        ss = ss * __expf(m - M) + s2 * __expf(m2 - M);
        m = M;
    }
    msv[idx] = make_float2(bl[idx & 255] - m, vbuf[idx] / (ss + 1.0f));
}

// ---------------------------------------------------------------------------
// Accum: recompute L', o += (L'+bl)*c.y * e^(L'+c.x) over 32 sk; plain
// stores of the 32x64 partial tile to po[chunk] (no atomics). NO LDS:
// af[2][8] (64 VGPRs) from L2, wl[2][8] resident. R12 tile (mt=2, nt=2).
// Grid (16 sq-tiles of 32, 2 d-halves, 16 chunks of 32) = 512 = 2/CU.
// ---------------------------------------------------------------------------
__global__ __launch_bounds__(256, 2) void accum_mfma(
    const _Float16* __restrict__ qh, const _Float16* __restrict__ kh,
    const _Float16* __restrict__ WlhT, const float* __restrict__ bl,
    const float2* __restrict__ msv, float* __restrict__ po)
{
    const int tid  = threadIdx.x;
    const int lane = tid & 63, wave = tid >> 6;
    const int quad = lane >> 4, l16 = lane & 15;
    const int sq0  = blockIdx.x * 32;
    const int dw   = blockIdx.y * 128 + wave * 32;
    const int chunk = blockIdx.z;
    const int sk0  = chunk * 32;

    half8 af[2][8];
    #pragma unroll
    for (int mt = 0; mt < 2; ++mt)
        #pragma unroll
        for (int kk = 0; kk < 8; ++kk)
            af[mt][kk] = *(const half8*)(qh +
                (size_t)(sq0 + mt * 16 + l16) * D_DIM + kk * 32 + quad * 8);

    half8 wl[2][8];
    #pragma unroll
    for (int nt = 0; nt < 2; ++nt) {
        const int d = dw + nt * 16 + l16;
        #pragma unroll
        for (int kk = 0; kk < 8; ++kk)
            wl[nt][kk] = *(const half8*)(WlhT + (size_t)d * D_DIM + kk * 32 + quad * 8);
    }
    float bl_r[2];
    #pragma unroll
    for (int nt = 0; nt < 2; ++nt)
        bl_r[nt] = bl[dw + nt * 16 + l16];

    floatx4 o[2][2];
    #pragma unroll
    for (int mt = 0; mt < 2; ++mt)
        #pragma unroll
        for (int nt = 0; nt < 2; ++nt)
            o[mt][nt] = (floatx4){0.f, 0.f, 0.f, 0.f};

    #pragma unroll 1
    for (int s = 0; s < 32; ++s) {
        const int sk = sk0 + s;
        floatx4 acc[2][2];
        #pragma unroll
        for (int mt = 0; mt < 2; ++mt)
            #pragma unroll
            for (int nt = 0; nt < 2; ++nt)
                acc[mt][nt] = (floatx4){0.f, 0.f, 0.f, 0.f};

        #pragma unroll
        for (int kk = 0; kk < 8; ++kk) {
            const half8 k8 = *(const half8*)(kh + (size_t)sk * D_DIM + kk * 32 + quad * 8);
            half8 bf[2];
            #pragma unroll
            for (int nt = 0; nt < 2; ++nt)
                bf[nt] = wl[nt][kk] * k8;
            #pragma unroll
            for (int mt = 0; mt < 2; ++mt)
                #pragma unroll
                for (int nt = 0; nt < 2; ++nt)
                    acc[mt][nt] = __builtin_amdgcn_mfma_f32_16x16x32_f16(
                        af[mt][kk], bf[nt], acc[mt][nt], 0, 0, 0);
        }

        #pragma unroll
        for (int nt = 0; nt < 2; ++nt) {
            const float2 c = msv[((size_t)sk << 8) + dw + nt * 16 + l16];
            #pragma unroll
            for (int mt = 0; mt < 2; ++mt)
                #pragma unroll
                for (int r = 0; r < 4; ++r) {
                    const float Lp = acc[mt][nt][r];
                    const float e  = __expf(Lp + c.x);       // e^(L-m)
                    const float u  = (Lp + bl_r[nt]) * c.y;  // L * v/(S+1)
                    o[mt][nt][r] = fmaf(u, e, o[mt][nt][r]);
                }
        }
    }

    float* dst = po + (size_t)chunk * SLICE;
    #pragma unroll
    for (int mt = 0; mt < 2; ++mt)
        #pragma unroll
        for (int nt = 0; nt < 2; ++nt)
            #pragma unroll
            for (int r = 0; r < 4; ++r) {
                const int row = sq0 + mt * 16 + quad * 4 + r;
                const int col = dw + nt * 16 + l16;
                dst[(size_t)row * D_DIM + col] = o[mt][nt][r];
            }
}

// ---------------------------------------------------------------------------
extern "C" void kernel_launch(void* const* d_in, const int* in_sizes, int n_in,
                              void* d_out, int out_size, void* d_ws, size_t ws_size,
                              hipStream_t stream)
{
    const float* query = (const float*)d_in[0];
    const float* key   = (const float*)d_in[1];
    const float* value = (const float*)d_in[2];
    const float* Wk  = (const float*)d_in[3];
    const float* bk  = (const float*)d_in[4];
    const float* Wq  = (const float*)d_in[5];
    const float* bq  = (const float*)d_in[6];
    const float* Wva = (const float*)d_in[7];
    const float* bva = (const float*)d_in[8];
    const float* Wl  = (const float*)d_in[9];
    const float* bl  = (const float*)d_in[10];
    const float* Wvo = (const float*)d_in[11];
    const float* bvo = (const float*)d_in[12];

    const int MAT = SLICE;                    // 131072
    float* ws   = (float*)d_ws;
    // R12/R17-proven footprint. msv in old mbuf slot; po overlays pm+ps.
    float* kbuf = ws;
    float* qbuf = ws + MAT;
    float* vbuf = ws + 2 * MAT;
    float2* msv = (float2*)(ws + 3 * MAT);                 // SLICE float2
    _Float16* WlhT = (_Float16*)(ws + 6 * MAT);            // 128 KB
    _Float16* kh   = (_Float16*)(ws + 6 * MAT + 32768);    // 256 KB
    _Float16* qh   = kh + MAT;                             // 256 KB
    float* pm  = ws + 6 * MAT + 32768 + 2 * 65536;         // 4 MB
    float* ps  = pm + 8 * MAT;                             // 4 MB
    float* po  = pm;   // 16*MAT floats (8 MB), pm/ps dead after reduce_ms
    float* out = (float*)d_out;

    prep_wl<<<256, 256, 0, stream>>>(Wl, WlhT);
    linres3<<<dim3(128, 3), 256, 0, stream>>>(key, Wk, bk, kbuf,
                                              query, Wq, bq, qbuf,
                                              value, Wva, bva, vbuf);
    cvt_fp16<<<128, 256, 0, stream>>>(kbuf, qbuf, kh, qh);

    stats_mfma<<<dim3(8, 4, 16), 256, 0, stream>>>(qh, kh, WlhT, bl, pm, ps);
    reduce_ms<<<512, 256, 0, stream>>>(pm, ps, vbuf, bl, msv);
    accum_mfma<<<dim3(16, 2, 16), 256, 0, stream>>>(qh, kh, WlhT, bl, msv, po);

    linres_sum<<<128, 256, 0, stream>>>(po, Wvo, bvo, out);
}